// Round 2
// baseline (674.972 us; speedup 1.0000x reference)
//
#include <hip/hip_runtime.h>
#include <stdint.h>

#define RDIM 14
#define CDIM 64
#define NFRAMES 4

// 4 waves/block. Each block stages a 512-row X tile into LDS (rows padded to
// 64B so compute reads are ds_read_b128); each wave computes 128 consecutive
// rows with lane = output column.
constexpr int BLOCK = 256;
constexpr int TILE_ROWS = 512;
constexpr int ROWS_PER_WAVE = TILE_ROWS / 4;            // 128
constexpr int ROW_PAD_FLOATS = 16;                      // 14 data + 2 pad = 64B
constexpr int X_TILE_BYTES = TILE_ROWS * ROW_PAD_FLOATS * 4;   // 32768 B
constexpr int CHUNK_BYTES = 16;
constexpr int N_CHUNKS = X_TILE_BYTES / CHUNK_BYTES;    // 2048
constexpr int ISSUES = N_CHUNKS / 64;                   // 32 wave-issues/block

typedef const __attribute__((address_space(1))) uint32_t* gptr_t;
typedef __attribute__((address_space(3))) uint32_t* lptr_t;

__global__ __launch_bounds__(BLOCK, 4) void frame_proj_kernel(
    const float* __restrict__ X,      // (batch, 14)
    const int* __restrict__ ids,      // (batch,)
    const float* __restrict__ W,      // (4, 64, 14)
    const float* __restrict__ B,      // (4, 64)
    float* __restrict__ out,          // (batch, 64)
    int batch)
{
    __shared__ float xs_lds[TILE_ROWS * ROW_PAD_FLOATS];   // 32 KB, 64B rows

    const int tid  = threadIdx.x;
    const int lane = tid & 63;
    const int wid  = __builtin_amdgcn_readfirstlane(tid >> 6);

    const int tileBase = blockIdx.x * TILE_ROWS;
    const int tileRows = min(TILE_ROWS, batch - tileBase);

    // ---- ids for this wave's 128 rows: two coalesced 256B loads ----
    const int waveRow0 = wid * ROWS_PER_WAVE;        // within tile
    const int gRow0    = tileBase + waveRow0;        // global row base
    int idv0 = 0, idv1 = 0;
    if (gRow0 + lane < batch)      idv0 = ids[gRow0 + lane];
    if (gRow0 + 64 + lane < batch) idv1 = ids[gRow0 + 64 + lane];

    // ---- stage X tile into LDS with 64B-padded rows ----
    // global_load_lds writes linearly (uniform base + lane*16), so the pad is
    // achieved by swizzling the per-lane GLOBAL source address: padded chunk c
    // holds global bytes 56*(c>>2) + (c&3)*16 (q==3 chunk drags 8B of the next
    // row into the pad, harmless). The q==3 chunk of the tile's last row reads
    // 8B past the tile -> use the safe path for the final block.
    if (tileBase + TILE_ROWS < batch) {
        const char* gsrc = (const char*)(X + (size_t)tileBase * RDIM);
        for (int i = wid; i < ISSUES; i += 4) {
            const int c = i * 64 + lane;
            const int r = c >> 2;
            const int q = c & 3;
            __builtin_amdgcn_global_load_lds(
                (gptr_t)(const void*)(gsrc + r * 56 + q * 16),
                (lptr_t)(void*)((char*)xs_lds + i * 1024),
                16, 0, 0);
        }
    } else {
        for (int i = tid; i < tileRows * ROW_PAD_FLOATS; i += BLOCK) {
            const int r = i >> 4, k = i & 15;
            xs_lds[i] = (k < RDIM) ? X[(size_t)(tileBase + r) * RDIM + k] : 0.0f;
        }
    }

    // ---- per-lane weight cache as float2 pairs (feeds v_pk_fma_f32) ----
    float2 w2[NFRAMES][7];
    float  bb[NFRAMES];
#pragma unroll
    for (int e = 0; e < NFRAMES; ++e) {
        const float2* wr = (const float2*)(W + (size_t)(e * CDIM + lane) * RDIM);
#pragma unroll
        for (int k = 0; k < 7; ++k) w2[e][k] = wr[k];
        bb[e] = B[e * CDIM + lane];
    }
    // Pin the cache in VGPRs: without this the compiler sinks the weight loads
    // into the row loop (round-0 kernel: VGPR_Count=32, cache never existed).
#pragma unroll
    for (int e = 0; e < NFRAMES; ++e) {
#pragma unroll
        for (int k = 0; k < 7; ++k) asm volatile("" : "+v"(w2[e][k]));
        asm volatile("" : "+v"(bb[e]));
    }

    __syncthreads();   // drains LDS-DMA + barrier

    const int nrows = min(ROWS_PER_WAVE, tileRows - waveRow0);
    const float4* xr4 = (const float4*)xs_lds + (size_t)waveRow0 * 4;
    float* orow = out + (size_t)gRow0 * CDIM + lane;

    auto body = [&](int r) {
        // Expert id: in-register, wave-uniform.
        const int id = (r < 64) ? __builtin_amdgcn_readlane(idv0, r & 63)
                                : __builtin_amdgcn_readlane(idv1, r & 63);

        // x row: 4x ds_read_b128 (64B-aligned padded row), uniform broadcast.
        float4 v0 = xr4[r * 4 + 0];
        float4 v1 = xr4[r * 4 + 1];
        float4 v2 = xr4[r * 4 + 2];
        float4 v3 = xr4[r * 4 + 3];
        float2 x2[7] = { {v0.x, v0.y}, {v0.z, v0.w}, {v1.x, v1.y}, {v1.z, v1.w},
                         {v2.x, v2.y}, {v2.z, v2.w}, {v3.x, v3.y} };

        auto dot = [&](const float2 (&wk)[7], float bias) {
            float ax = bias, ay = 0.0f;       // two chains -> v_pk_fma_f32
#pragma unroll
            for (int k = 0; k < 7; ++k) {
                ax = fmaf(x2[k].x, wk[k].x, ax);
                ay = fmaf(x2[k].y, wk[k].y, ay);
            }
            return ax + ay;
        };

        float acc;
        if (id == 0)      acc = dot(w2[0], bb[0]);
        else if (id == 1) acc = dot(w2[1], bb[1]);
        else if (id == 2) acc = dot(w2[2], bb[2]);
        else              acc = dot(w2[3], bb[3]);

        orow[(size_t)r * CDIM] = acc;   // 256B coalesced store per row
    };

    if (nrows == ROWS_PER_WAVE) {
#pragma unroll 2
        for (int r = 0; r < ROWS_PER_WAVE; ++r) body(r);
    } else {
        for (int r = 0; r < nrows; ++r) body(r);
    }
}

extern "C" void kernel_launch(void* const* d_in, const int* in_sizes, int n_in,
                              void* d_out, int out_size, void* d_ws, size_t ws_size,
                              hipStream_t stream) {
    const float* X   = (const float*)d_in[0];
    const int*   ids = (const int*)d_in[1];
    const float* W   = (const float*)d_in[2];
    const float* B   = (const float*)d_in[3];
    float* out = (float*)d_out;

    const int batch = in_sizes[1];  // frame_type_ids element count

    const int grid = (batch + TILE_ROWS - 1) / TILE_ROWS;
    frame_proj_kernel<<<grid, BLOCK, 0, stream>>>(X, ids, W, B, out, batch);
}

// Round 3
// 632.427 us; speedup vs baseline: 1.0673x; 1.0673x over previous
//
#include <hip/hip_runtime.h>
#include <stdint.h>

#define RDIM 14
#define CDIM 64
#define NFRAMES 4

// 4 waves/block. Each block stages a 256-row X tile into LDS with linear,
// fully-aligned async DMA (round-1 structure, measured ~150us); each wave
// computes 64 consecutive rows with lane = output column. New vs round-1:
// rows are consumed in PAIRS (2 rows = 112B = 7x aligned ds_read_b128) and
// the dot product is forced to v_pk_fma_f32 (7 packed FMAs/row).
constexpr int BLOCK = 256;
constexpr int TILE_ROWS = 256;
constexpr int ROWS_PER_WAVE = 64;
constexpr int X_TILE_BYTES = TILE_ROWS * RDIM * 4;        // 14336 B
constexpr int CHUNK_BYTES  = 64 * 16;                     // 1024 B per wave-issue
constexpr int N_CHUNKS     = X_TILE_BYTES / CHUNK_BYTES;  // 14

typedef const __attribute__((address_space(1))) uint32_t* gptr_t;
typedef __attribute__((address_space(3))) uint32_t* lptr_t;

__global__ __launch_bounds__(BLOCK, 4) void frame_proj_kernel(
    const float* __restrict__ X,      // (batch, 14)
    const int* __restrict__ ids,      // (batch,)
    const float* __restrict__ W,      // (4, 64, 14)
    const float* __restrict__ B,      // (4, 64)
    float* __restrict__ out,          // (batch, 64)
    int batch)
{
    __shared__ float xs_lds[TILE_ROWS * RDIM];   // 14336 B, packed 56 B rows

    const int tid  = threadIdx.x;
    const int lane = tid & 63;
    const int wid  = __builtin_amdgcn_readfirstlane(tid >> 6);

    const int tileBase = blockIdx.x * TILE_ROWS;
    const int tileRows = min(TILE_ROWS, batch - tileBase);

    // ---- ids for this wave's 64 rows: one coalesced 256B load into a VGPR ----
    const int waveRow0 = wid * ROWS_PER_WAVE;        // within tile
    const int gRow0    = tileBase + waveRow0;        // global row base
    int idv = 0;
    if (gRow0 + lane < batch) idv = ids[gRow0 + lane];

    // ---- stage X tile into LDS: linear layout, every issue 16B-aligned ----
    if (tileRows == TILE_ROWS) {
        const char* gsrc = (const char*)(X + (size_t)tileBase * RDIM);
        for (int c = wid; c < N_CHUNKS; c += 4) {
            __builtin_amdgcn_global_load_lds(
                (gptr_t)(const void*)(gsrc + c * CHUNK_BYTES + lane * 16),
                (lptr_t)(void*)((char*)xs_lds + c * CHUNK_BYTES),
                16, 0, 0);
        }
    } else {
        for (int i = tid; i < tileRows * RDIM; i += BLOCK)
            xs_lds[i] = X[(size_t)tileBase * RDIM + i];
    }

    // ---- per-lane weight cache as float2 pairs (operands for v_pk_fma) ----
    float2 w2[NFRAMES][7];
    float  bb[NFRAMES];
#pragma unroll
    for (int e = 0; e < NFRAMES; ++e) {
        const float2* wr = (const float2*)(W + (size_t)(e * CDIM + lane) * RDIM);
#pragma unroll
        for (int k = 0; k < 7; ++k) w2[e][k] = wr[k];
        bb[e] = B[e * CDIM + lane];
    }
    // Pin the cache in VGPRs: without this the compiler sinks the weight loads
    // into the row loop (round-0 kernel: VGPR_Count=32, cache never existed).
#pragma unroll
    for (int e = 0; e < NFRAMES; ++e) {
#pragma unroll
        for (int k = 0; k < 7; ++k) asm volatile("" : "+v"(w2[e][k]));
        asm volatile("" : "+v"(bb[e]));
    }

    __syncthreads();   // drains LDS-DMA + barrier

    const int nrows = min(ROWS_PER_WAVE, tileRows - waveRow0);
    // waveRow0*56 is a multiple of 16 (64*56=3584), so every even-row pair
    // below starts 16B-aligned.
    const float4* xr4 = (const float4*)((const char*)xs_lds + waveRow0 * (RDIM * 4));
    float* orow = out + (size_t)gRow0 * CDIM + lane;

    // 7 packed FMAs: acc = {bias,0}; acc.xy += x.xy * w.xy; result = acc.x+acc.y
    auto dot = [&](const float2 (&xp)[7], const float2 (&wk)[7], float bias) {
        float2 acc; acc.x = bias; acc.y = 0.0f;
#pragma unroll
        for (int k = 0; k < 7; ++k)
            asm("v_pk_fma_f32 %0, %1, %2, %0" : "+v"(acc) : "v"(xp[k]), "v"(wk[k]));
        return acc.x + acc.y;
    };

    auto sel = [&](const float2 (&xp)[7], int id) {
        if (id == 0)      return dot(xp, w2[0], bb[0]);   // wave-uniform branch
        else if (id == 1) return dot(xp, w2[1], bb[1]);
        else if (id == 2) return dot(xp, w2[2], bb[2]);
        else              return dot(xp, w2[3], bb[3]);
    };

    const int npairs = (nrows + 1) >> 1;
    for (int p = 0; p < npairs; ++p) {
        const int r0 = 2 * p;
        // rows r0,r0+1 = 112B = 7x ds_read_b128, uniform broadcast address.
        float4 v0 = xr4[p * 7 + 0];
        float4 v1 = xr4[p * 7 + 1];
        float4 v2 = xr4[p * 7 + 2];
        float4 v3 = xr4[p * 7 + 3];
        float4 v4 = xr4[p * 7 + 4];
        float4 v5 = xr4[p * 7 + 5];
        float4 v6 = xr4[p * 7 + 6];

        const int id0 = __builtin_amdgcn_readlane(idv, r0);
        const int id1 = __builtin_amdgcn_readlane(idv, r0 + 1);

        float2 xa[7] = { {v0.x, v0.y}, {v0.z, v0.w}, {v1.x, v1.y}, {v1.z, v1.w},
                         {v2.x, v2.y}, {v2.z, v2.w}, {v3.x, v3.y} };
        orow[(size_t)r0 * CDIM] = sel(xa, id0);   // 256B coalesced store

        if (r0 + 1 < nrows) {
            float2 xb[7] = { {v3.z, v3.w}, {v4.x, v4.y}, {v4.z, v4.w}, {v5.x, v5.y},
                             {v5.z, v5.w}, {v6.x, v6.y}, {v6.z, v6.w} };
            orow[(size_t)(r0 + 1) * CDIM] = sel(xb, id1);
        }
    }
}

extern "C" void kernel_launch(void* const* d_in, const int* in_sizes, int n_in,
                              void* d_out, int out_size, void* d_ws, size_t ws_size,
                              hipStream_t stream) {
    const float* X   = (const float*)d_in[0];
    const int*   ids = (const int*)d_in[1];
    const float* W   = (const float*)d_in[2];
    const float* B   = (const float*)d_in[3];
    float* out = (float*)d_out;

    const int batch = in_sizes[1];  // frame_type_ids element count

    const int grid = (batch + TILE_ROWS - 1) / TILE_ROWS;
    frame_proj_kernel<<<grid, BLOCK, 0, stream>>>(X, ids, W, B, out, batch);
}